// Round 11
// baseline (162.820 us; speedup 1.0000x reference)
//
#include <hip/hip_runtime.h>

// SSIM loss v18: dual-pipe tap sourcing (LDS + L1) on the v15 base.
// 11-round model: per-output VALU issue (~400-425 cyc) is at the packed-math
// floor; total time bounces between ~730 cyc/step (all taps via LDS: pipe
// ~85-100%) and ~770-810 (all taps via L1 gather: pipe >100%). The two pipes
// are independent HW and no variant used both. v18 splits: taps 0..6 from
// LDS (7 ds_read_b64, 56 B/lane), taps 7..10 (cols i+2..i+5) via one
// per-lane dwordx4 per image from L1 (prefetched with the row pipeline).
// Right-edge exactness via v16's verified clamp + shifted-weight fold
// (per-lane wq[4], zeroed for clamped taps); row mask folded into merge
// fmas (no extra masking inst). Halo staging shrinks to 6 cols (taps<=6).
// Predicted: VALUBusy 54->62-70%, kernel 67.5->58-63us, FETCH ~63.6MB,
// WRITE ~24KB (spill tripwire), conflicts 0.

#define BATCH  16
#define CHAN   3
#define H_     512
#define W_     512
#define HW     (H_ * W_)
#define CH_H   64
#define NPIX   ((long)BATCH*CHAN*H_*W_)

// Normalized 11-tap Gaussian, sigma=1.5 (constants gave absmax 0 in v1/v2/v6).
#define GW0 0.0010284f
#define GW1 0.0075988f
#define GW2 0.0360008f
#define GW3 0.1093554f
#define GW4 0.2130056f
#define GW5 0.2660117f

typedef float v2  __attribute__((ext_vector_type(2)));
typedef float v4f __attribute__((ext_vector_type(4)));

__device__ __forceinline__ float wgk(int k) {  // k literal -> constant
    return (k == 0 || k == 10) ? GW0
         : (k == 1 || k == 9)  ? GW1
         : (k == 2 || k == 8)  ? GW2
         : (k == 3 || k == 7)  ? GW3
         : (k == 4 || k == 6)  ? GW4 : GW5;
}

__device__ __forceinline__ v2 pfma(v2 a, v2 b, v2 c) {
#if __has_builtin(__builtin_elementwise_fma)
    return __builtin_elementwise_fma(a, b, c);
#else
    v2 r; r.x = fmaf(a.x, b.x, c.x); r.y = fmaf(a.y, b.y, c.y); return r;
#endif
}
__device__ __forceinline__ v2 psfma(float s, v2 b, v2 c) {  // (s,s)*b + c
    v2 sv; sv.x = s; sv.y = s;
    return pfma(sv, b, c);
}

__device__ __forceinline__ float ssim_retire(float mu1, float mu2,
                                             float x11, float x22, float x12) {
    const float c1 = 1.0e-4f;
    const float c2 = 9.0e-4f;
    float mu1s = mu1 * mu1;
    float mu2s = mu2 * mu2;
    float m12  = mu1 * mu2;
    float num  = (2.0f * m12 + c1) * (2.0f * (x12 - m12) + c2);
    float den  = (mu1s + mu2s + c1) * ((x11 - mu1s) + (x22 - mu2s) + c2);
#if __has_builtin(__builtin_amdgcn_rcpf)
    float l = 1.0f - num * __builtin_amdgcn_rcpf(den);   // v_rcp_f32, ~1 ulp
#else
    float l = 1.0f - num / den;
#endif
    return fminf(fmaxf(l, 0.0f), 1.0f);
}

// Slot i state: P=(mu1,mu2) packed, Q=(x11,x22) packed, E=x12 scalar.
#define DECL(i) v2 P##i = {0.f, 0.f}, Q##i = {0.f, 0.f}; float E##i = 0.f
#define ACCI(i) do { const float wj_ = wgk(10 - (i));            \
    P##i = psfma(wj_, hmm, P##i);                                \
    Q##i = psfma(wj_, hss, Q##i);                                \
    E##i = fmaf(wj_, hmx, E##i); } while (0)
#define SHIFT(i, j) P##i = P##j; Q##i = Q##j; E##i = E##j

__global__ __launch_bounds__(256, 3) void ssim_kernel(const float* __restrict__ img1,
                                                      const float* __restrict__ img2,
                                                      float* __restrict__ out) {
    // Double-buffered per-wave staging: 2 x 80 interleaved (img1,img2) pairs.
    __shared__ __align__(16) v2 sp[4][2][80];   // entries 0..69 used
    __shared__ float wsum[4];

    const int tid  = threadIdx.x;
    const int lane = tid & 63;
    const int wv   = tid >> 6;

    const int wid   = blockIdx.x * 4 + wv;     // 0..3071
    const int plane = wid >> 6;
    const int rem   = wid & 63;
    const int strip = rem & 7;
    const int chunk = rem >> 3;
    const int y0 = chunk * CH_H;
    const int c0 = strip * 64;

    // st[par][i] <-> col c0-5+i of (img1,img2), i = 0..69 (taps 0..6 only).
    const int  colg  = c0 - 5 + lane;          // only <0 can be OOB (max 507)
    const bool colOk = (colg >= 0);
    const int  colC  = colOk ? colg : 0;
    const int  colg2  = c0 + 59 + lane;        // halo cols c0+59..c0+64, lanes 0..5
    const bool colOk2 = (lane < 6) && (colg2 < W_);
    const int  col2C  = colOk2 ? colg2 : 0;

    // L1 quad: taps 7..10 = cols i+2..i+5, i = c0+lane. Base clamped to
    // W-4; shift folds into per-lane weights wq[j] (0 for clamped/OOB taps).
    const int  iq  = c0 + lane;
    const int  bq  = iq + 2;
    const int  bqc = min(bq, W_ - 4);
    float wq0, wq1, wq2, wq3;
    {
        int k0 = bqc - iq + 5;                 // tap index of quad float 0
        float w[4];
#pragma unroll
        for (int j = 0; j < 4; ++j) {
            int k = k0 + j;                    // 2..10
            float ww = 0.0f;
            ww = (k == 7)  ? GW3 : ww;
            ww = (k == 8)  ? GW2 : ww;
            ww = (k == 9)  ? GW1 : ww;
            ww = (k == 10) ? GW0 : ww;
            w[j] = ww;                         // k<7 -> 0 (LDS covers those)
        }
        wq0 = w[0]; wq1 = w[1]; wq2 = w[2]; wq3 = w[3];
    }
    const v2 wqp0 = {wq0, wq1}, wqp1 = {wq2, wq3};

    const size_t pb = (size_t)plane * HW;
    const float* __restrict__ p1  = img1 + pb + colC;
    const float* __restrict__ p2  = img2 + pb + colC;
    const float* __restrict__ p1b = img1 + pb + col2C;
    const float* __restrict__ p2b = img2 + pb + col2C;
    const float* __restrict__ p1q = img1 + pb + bqc;
    const float* __restrict__ p2q = img2 + pb + bqc;

    v2 (*st)[80] = sp[wv];

    DECL(0); DECL(1); DECL(2); DECL(3); DECL(4); DECL(5);
    DECL(6); DECL(7); DECL(8); DECL(9); DECL(10);
    float lsum = 0.0f;

    // Row pipeline: staged pair (cv*), halo pair (cv*b), quads (qa,qb), row
    // mask rmC for the quads. Preload for r = y0 - 5.
    float cv1, cv2, cv1b, cv2b, rmC;
    v4f qa, qb;
    {
        int r = y0 - 5;
        bool rok = (unsigned)r < (unsigned)H_;
        size_t off = (size_t)(rok ? r : 0) * W_;
        cv1  = (rok && colOk)  ? p1[off]  : 0.0f;
        cv2  = (rok && colOk)  ? p2[off]  : 0.0f;
        cv1b = (rok && colOk2) ? p1b[off] : 0.0f;
        cv2b = (rok && colOk2) ? p2b[off] : 0.0f;
        qa = *(const v4f*)(p1q + off);
        qb = *(const v4f*)(p2q + off);
        rmC = rok ? 1.0f : 0.0f;
    }

#pragma unroll 1
    for (int sb = 0; sb < 37; ++sb) {
#pragma unroll
        for (int j = 0; j < 2; ++j) {
            const int step = sb * 2 + j;
            const int par  = j;                // compile-time buffer parity
            const int yy = step - 10;          // output row retired this step

            // 1. Stage current h-row into buffer `par` (70 col-pairs).
            {
                v2 v; v.x = cv1; v.y = cv2;
                st[par][lane] = v;
                if (lane < 6) { v2 vb; vb.x = cv1b; vb.y = cv2b; st[par][64 + lane] = vb; }
            }
            __asm__ __volatile__("" ::: "memory");   // writes before reads

            // 2. Prefetch next h-row (r = y0 + yy + 6); independent of step.
            v4f nqa, nqb; float rmN;
            {
                int r = y0 + yy + 6;
                bool rok = (unsigned)r < (unsigned)H_;
                size_t off = (size_t)(rok ? r : 0) * W_;
                cv1  = (rok && colOk)  ? p1[off]  : 0.0f;
                cv2  = (rok && colOk)  ? p2[off]  : 0.0f;
                cv1b = (rok && colOk2) ? p1b[off] : 0.0f;
                cv2b = (rok && colOk2) ? p2b[off] : 0.0f;
                nqa = *(const v4f*)(p1q + off);
                nqb = *(const v4f*)(p2q + off);
                rmN = rok ? 1.0f : 0.0f;
            }

            // 3a. Horizontal taps 0..6 from LDS (packed image-interleaved).
            v2 hmm = {0.f, 0.f}, hss = {0.f, 0.f};
            float hmx = 0.f;
#pragma unroll
            for (int k = 0; k < 7; ++k) {
                v2 ab = st[par][lane + k];     // ds_read_b64, imm offset
                float wk = wgk(k);
                v2 t = ab;
                t.x *= wk; t.y *= wk;          // pk_mul (t1,t2)
                hmm += t;                      // pk_add
                hss = pfma(t, ab, hss);        // pk_fma -> (m11,m22)
                hmx = fmaf(t.x, ab.y, hmx);    // scalar cross term
            }
            __asm__ __volatile__("" ::: "memory");   // iter j+2 writes stay after reads

            // 3b. Horizontal taps 7..10 from register quads (tap-axis packed).
            //     Quad floats (j) pair as (0,1),(2,3); weights wqp0/wqp1
            //     already encode edge clamping. Row mask rmC folds into merge.
            {
                v2 pa0 = {qa.x, qa.y}, pa1 = {qa.z, qa.w};
                v2 pb0 = {qb.x, qb.y}, pb1 = {qb.z, qb.w};
                v2 ta0 = wqp0 * pa0, tb0 = wqp0 * pb0;
                v2 ta1 = wqp1 * pa1, tb1 = wqp1 * pb1;
                v2 s1  = ta0 + ta1;                    // img1 mean partial
                v2 s2  = tb0 + tb1;                    // img2 mean partial
                v2 s11 = pfma(ta0, pa0, ta1 * pa1);    // img1 sq partial
                v2 s22 = pfma(tb0, pb0, tb1 * pb1);    // img2 sq partial
                v2 s12 = pfma(ta0, pb0, ta1 * pb1);    // cross partial
                hmm.x = fmaf(rmC, s1.x + s1.y, hmm.x);
                hmm.y = fmaf(rmC, s2.x + s2.y, hmm.y);
                hss.x = fmaf(rmC, s11.x + s11.y, hss.x);
                hss.y = fmaf(rmC, s22.x + s22.y, hss.y);
                hmx   = fmaf(rmC, s12.x + s12.y, hmx);
            }

            // 4. Accumulate into the 11 in-flight output rows.
            ACCI(0); ACCI(1); ACCI(2); ACCI(3); ACCI(4); ACCI(5);
            ACCI(6); ACCI(7); ACCI(8); ACCI(9); ACCI(10);

            // 5. Retire output row yy (slot 0 complete).
            if (yy >= 0) lsum += ssim_retire(P0.x, P0.y, Q0.x, Q0.y, E0);

            // 6. Shift the register ring (pure SSA renames; unroll elides half).
            SHIFT(0, 1); SHIFT(1, 2); SHIFT(2, 3); SHIFT(3, 4); SHIFT(4, 5);
            SHIFT(5, 6); SHIFT(6, 7); SHIFT(7, 8); SHIFT(8, 9); SHIFT(9, 10);
            P10 = (v2){0.f, 0.f}; Q10 = (v2){0.f, 0.f}; E10 = 0.f;

            // 7. Advance quad pipeline (renames away under the unrolled pair).
            qa = nqa; qb = nqb; rmC = rmN;
        }
    }

    // Reduction: wave shuffle -> LDS -> one atomic per block.
#pragma unroll
    for (int off = 32; off > 0; off >>= 1) lsum += __shfl_down(lsum, off);
    if (lane == 0) wsum[wv] = lsum;
    __syncthreads();
    if (tid == 0) {
        float bs = wsum[0] + wsum[1] + wsum[2] + wsum[3];
        atomicAdd(out, bs * (0.5f / (float)NPIX));
    }
}

extern "C" void kernel_launch(void* const* d_in, const int* in_sizes, int n_in,
                              void* d_out, int out_size, void* d_ws, size_t ws_size,
                              hipStream_t stream) {
    const float* img1 = (const float*)d_in[0];
    const float* img2 = (const float*)d_in[1];
    float* out = (float*)d_out;

    hipMemsetAsync(out, 0, sizeof(float), stream);

    // 8 strips x 8 chunks x 48 planes = 3072 waves = 768 blocks = 3/CU.
    ssim_kernel<<<dim3(8 * 8 * BATCH * CHAN / 4), 256, 0, stream>>>(img1, img2, out);
}